// Round 11
// baseline (1123.992 us; speedup 1.0000x reference)
//
#include <hip/hip_runtime.h>

#define N_NODES 100000
#define N1 (N_NODES + 1)
#define N_EDGES 3200000
#define N_GRAPHS 1000
#define IN_DIM 10
#define HIDDEN 64
#define NQUADS (N_NODES / 4)    // 25000 exact
#define NB_GATHER (NQUADS / 4)  // 6250 blocks per gather pass (4 quads/block)

#define NRANGES 8
#define RANGE_SIZE ((N_NODES + NRANGES - 1) / NRANGES)
#define CHUNK_EDGES 4096

#define SLC8 ((size_t)N1 * 8)    // u32 per bf16 slice table slice ([N1][8] u32 = 16 bf16 dims)
#define SLC16 ((size_t)N1 * 16)  // f32 per agg slice ([N1][16] f32)

typedef float f32x4 __attribute__((ext_vector_type(4)));
typedef float f32x2 __attribute__((ext_vector_type(2)));
typedef unsigned int u32;
typedef unsigned int u32x2 __attribute__((ext_vector_type(2)));

// bf16 helpers: RNE pack of 2 floats into one u32; unpack lo/hi
__device__ __forceinline__ u32 rne1(float a) {
    u32 u = __float_as_uint(a);
    return (u + 0x7fffu + ((u >> 16) & 1u)) >> 16;
}
__device__ __forceinline__ u32 rne_pack(float a, float b) {
    return rne1(a) | (rne1(b) << 16);
}
__device__ __forceinline__ float bf_lo(u32 w) { return __uint_as_float(w << 16); }
__device__ __forceinline__ float bf_hi(u32 w) { return __uint_as_float(w & 0xffff0000u); }

// ---------------- degree histogram ----------------
__global__ void k_deg(const int* __restrict__ col, int* __restrict__ deg) {
    int e = blockIdx.x * blockDim.x + threadIdx.x;
    if (e < N_EDGES) atomicAdd(&deg[col[e]], 1);
}

// ---------------- hierarchical exclusive scan (offsets) ----------------
__global__ __launch_bounds__(1024) void k_scan_block(const int* __restrict__ deg,
                                                     int* __restrict__ offs,
                                                     int* __restrict__ bsums) {
    __shared__ int s[1024];
    int t = threadIdx.x;
    int i = blockIdx.x * 1024 + t;
    int v = (i < N_NODES) ? deg[i] : 0;
    s[t] = v;
    __syncthreads();
    for (int d = 1; d < 1024; d <<= 1) {
        int x = (t >= d) ? s[t - d] : 0;
        __syncthreads();
        s[t] += x;
        __syncthreads();
    }
    if (i < N_NODES) offs[i] = s[t] - v;
    if (t == 1023) bsums[blockIdx.x] = s[t];
}

__global__ __launch_bounds__(128) void k_scan_top(int* __restrict__ bsums, int nb) {
    __shared__ int s[128];
    int t = threadIdx.x;
    int v = (t < nb) ? bsums[t] : 0;
    s[t] = v;
    __syncthreads();
    for (int d = 1; d < 128; d <<= 1) {
        int x = (t >= d) ? s[t - d] : 0;
        __syncthreads();
        s[t] += x;
        __syncthreads();
    }
    if (t < nb) bsums[t] = s[t] - v;
}

__global__ __launch_bounds__(1024) void k_scan_add(int* __restrict__ offs,
                                                   const int* __restrict__ bsums) {
    int i = blockIdx.x * 1024 + threadIdx.x;
    if (i < N_NODES) offs[i] += bsums[blockIdx.x];
}

// ---------------- dinv ----------------
__global__ void k_dinv(const int* __restrict__ deg, float* __restrict__ dinv) {
    int n = blockIdx.x * blockDim.x + threadIdx.x;
    if (n < N_NODES) {
        int d = deg[n];
        dinv[n] = (d > 0) ? rsqrtf((float)d) : 0.f;
    }
}

// ---------------- CSR fill, XCD-range-partitioned ----------------
__global__ __launch_bounds__(256) void k_fill(const int* __restrict__ row,
                                              const int* __restrict__ col,
                                              const int* __restrict__ offs,
                                              int* __restrict__ cursor,
                                              int* __restrict__ csr_src) {
    int range = blockIdx.x & (NRANGES - 1);
    int chunk = blockIdx.x >> 3;
    int lo = range * RANGE_SIZE;
    int hi = lo + RANGE_SIZE;
    int base = chunk * CHUNK_EDGES + threadIdx.x;
#pragma unroll
    for (int k = 0; k < CHUNK_EDGES / 256; ++k) {
        int e = base + k * 256;
        if (e < N_EDGES) {
            int c = col[e];
            if (c >= lo && c < hi) {
                int r = row[e];
                int p = atomicAdd(&cursor[c], 1);
                csr_src[offs[c] + p] = r;
            }
        }
    }
}

// ---------------- degree counting-sort: hist -> scan -> place ----------------
__global__ void k_hist(const int* __restrict__ deg, int* __restrict__ hist) {
    int n = blockIdx.x * blockDim.x + threadIdx.x;
    if (n < N_NODES) atomicAdd(&hist[min(deg[n], 255)], 1);
}

__global__ __launch_bounds__(256) void k_hscan(int* __restrict__ hist, int* __restrict__ cur) {
    __shared__ int s[256];
    int t = threadIdx.x;
    int v = hist[t];
    s[t] = v;
    __syncthreads();
    for (int d = 1; d < 256; d <<= 1) {
        int x = (t >= d) ? s[t - d] : 0;
        __syncthreads();
        s[t] += x;
        __syncthreads();
    }
    cur[t] = s[t] - v;
}

__global__ void k_place(const int* __restrict__ deg, int* __restrict__ cur,
                        int* __restrict__ sorted) {
    int n = blockIdx.x * blockDim.x + threadIdx.x;
    if (n < N_NODES) {
        int b = min(deg[n], 255);
        int p = atomicAdd(&cur[b], 1);
        sorted[p] = n;
    }
}

// ---------------- prescale x*dinv into bf16 table [N1][8] u32 (16 dims, 10 real) --------
__global__ void k_prex(const float* __restrict__ x, const float* __restrict__ dinv,
                       u32* __restrict__ xsb) {
    int i = blockIdx.x * blockDim.x + threadIdx.x;
    if (i >= (int)(N1 * 8)) return;
    int n = i >> 3, cc = i & 7;
    float v0 = 0.f, v1 = 0.f;
    if (n < N_NODES) {
        float di = dinv[n];
        int d0 = cc * 2, d1 = cc * 2 + 1;
        if (d0 < IN_DIM) v0 = x[n * IN_DIM + d0] * di;
        if (d1 < IN_DIM) v1 = x[n * IN_DIM + d1] * di;
    }
    xsb[i] = rne_pack(v0, v1);  // row N_NODES -> zeros (gather sink)
}

// ---------------- zero the gather-sink rows of both h slice tables ----------------
__global__ void k_zerosink(u32* __restrict__ h1, u32* __restrict__ h2) {
    int t = threadIdx.x;  // 64
    u32* p = (t < 32) ? h1 : h2;
    int r = t & 31;
    p[((size_t)(r >> 3) * N1 + N_NODES) * 8 + (r & 7)] = 0;
}

// ---------------- graph boundaries (batch is sorted) ----------------
__global__ void k_bounds(const int* __restrict__ batch, int* __restrict__ gmin,
                         int* __restrict__ gmax) {
    int n = blockIdx.x * blockDim.x + threadIdx.x;
    if (n < N_NODES) {
        int g = batch[n];
        atomicMin(&gmin[g], n);
        atomicMax(&gmax[g], n + 1);
    }
}

// ============ gather: bf16 slice table, 8-lane coalesced 32B row reads ============
// grid = NPASS * NB_GATHER, pass-major (blocks of pass p dispatch contiguously so each
// XCD's L2 holds one 3.2MB slice). Wave = 4 nodes x 16 lanes; per node the 16 lanes
// split into 2 half-groups of 8; per j-step each half-group reads ONE 32B row
// (8 lanes x u32, 1 cache line) -> 8 lines/wave-instr, 8 loads in flight.
// csr via NT loads, agg via NT full-line stores: neither evicts the resident table.
__global__ __launch_bounds__(256) void k_gather(const u32* __restrict__ tab,  // [P][N1][8]
                                                const int* __restrict__ offs,
                                                const int* __restrict__ deg,
                                                const int* __restrict__ csr,
                                                const int* __restrict__ sorted,
                                                float* __restrict__ agg) {    // [P][N1][16]
    int bip = blockIdx.x % NB_GATHER;
    int pass = blockIdx.x / NB_GATHER;
    const u32* tabp = tab + (size_t)pass * SLC8;
    float* aggp = agg + (size_t)pass * SLC16;

    int lane = threadIdx.x & 63;
    int f = lane & 15;   // slot within node group
    int gbase = lane & 48;
    int e2 = f >> 3;     // half-group (edge parity)
    int c = f & 7;       // u32 column (dims 2c, 2c+1)

    int quad = bip * 4 + (threadIdx.x >> 6);
    int n = sorted[quad * 4 + (lane >> 4)];
    int start = offs[n], dn = deg[n];

    float ax = 0.f, ay = 0.f;
    for (int base = 0; base < dn; base += 16) {
        int sv = __builtin_nontemporal_load(&csr[start + base + f]);
        sv = (base + f < dn) ? sv : N_NODES;  // sink row = zeros
        u32 w[8];
#pragma unroll
        for (int j = 0; j < 8; ++j) {
            int sj = __shfl(sv, gbase + j * 2 + e2);
            w[j] = tabp[(size_t)sj * 8 + c];
        }
#pragma unroll
        for (int j = 0; j < 8; ++j) {
            ax += bf_lo(w[j]);
            ay += bf_hi(w[j]);
        }
    }
    // combine the two half-groups (lanes f and f^8 share c)
    ax += __shfl_xor(ax, 8);
    ay += __shfl_xor(ay, 8);
    if (e2 == 0) {
        f32x2 v = {ax, ay};
        __builtin_nontemporal_store(v, (f32x2*)&aggp[(size_t)n * 16 + c * 2]);
    }
}

// ============ dense 1: agg1(16 padded dims)*dinv @ W1 + b1, relu, *dinv -> bf16 table ====
__global__ __launch_bounds__(256) void k_dense1(const float* __restrict__ agg,  // [N1][16]
                                                const float* __restrict__ dinv,
                                                const float* __restrict__ W1,
                                                const float* __restrict__ b1,
                                                u32* __restrict__ htab) {       // [4][N1][8]
    int lane = threadIdx.x & 63;
    float W1reg[16];
#pragma unroll
    for (int k = 0; k < 16; ++k) W1reg[k] = (k < IN_DIM) ? W1[k * HIDDEN + lane] : 0.f;
    float b1reg = b1[lane];
    int wid = (blockIdx.x * 256 + threadIdx.x) >> 6;
    int nwaves = gridDim.x * 4;
    for (int quad = wid; quad < NQUADS; quad += nwaves) {
        int n = quad * 4 + (lane >> 4);
        float a = agg[(size_t)n * 16 + (lane & 15)] * dinv[n];
#pragma unroll
        for (int g = 0; g < 4; ++g) {
            float o = b1reg;
#pragma unroll
            for (int k = 0; k < 16; ++k) o += __shfl(a, g * 16 + k) * W1reg[k];
            int ng = quad * 4 + g;
            o = fmaxf(o, 0.f) * dinv[ng];
            float other = __shfl_xor(o, 1);  // partner dim (lane^1)
            if (!(lane & 1)) {
                // dim = lane: slice p = lane>>4, u32 col = (lane&15)>>1
                htab[(size_t)(lane >> 4) * SLC8 + (size_t)ng * 8 + ((lane & 15) >> 1)] =
                    rne_pack(o, other);
            }
        }
    }
}

// ============ dense 2: agg2(64)*dinv @ W + b, relu, *dinv -> bf16 slice table ============
__global__ __launch_bounds__(256) void k_dense2(const float* __restrict__ agg,  // [4][N1][16]
                                                const float* __restrict__ dinv,
                                                const float* __restrict__ W,
                                                const float* __restrict__ b,
                                                u32* __restrict__ htab) {       // [4][N1][8]
    __shared__ f32x4 sW4[HIDDEN][16];
    for (int i = threadIdx.x; i < HIDDEN * 16; i += 256) {
        int k = i >> 4, ff = i & 15;
        sW4[k][ff] = *(const f32x4*)&W[k * HIDDEN + ff * 4];
    }
    __syncthreads();
    int lane = threadIdx.x & 63;
    int f = lane & 15, gbase = lane & 48;
    f32x4 b4 = *(const f32x4*)&b[f * 4];
    int wid = (blockIdx.x * 256 + threadIdx.x) >> 6;
    int nwaves = gridDim.x * 4;
    for (int quad = wid; quad < NQUADS; quad += nwaves) {
        int n = quad * 4 + (lane >> 4);
        float di = dinv[n];
        // dims f*4..f*4+3 live in slice f>>2 at f32 offset (f&3)*4
        f32x4 acc = *(const f32x4*)&agg[(size_t)(f >> 2) * SLC16 + (size_t)n * 16 + (f & 3) * 4];
        acc *= di;
        f32x4 out = b4;
#pragma unroll
        for (int k = 0; k < HIDDEN; ++k) {
            float srcv = (k & 3) == 0 ? acc.x : (k & 3) == 1 ? acc.y : (k & 3) == 2 ? acc.z : acc.w;
            float ak = __shfl(srcv, gbase + (k >> 2));
            out += ak * sW4[k][f];
        }
        out.x = fmaxf(out.x, 0.f) * di;
        out.y = fmaxf(out.y, 0.f) * di;
        out.z = fmaxf(out.z, 0.f) * di;
        out.w = fmaxf(out.w, 0.f) * di;
        u32x2 pv;
        pv.x = rne_pack(out.x, out.y);
        pv.y = rne_pack(out.z, out.w);
        *(u32x2*)&htab[(size_t)(f >> 2) * SLC8 + (size_t)n * 8 + (f & 3) * 2] = pv;
    }
}

// ============ pool: gpool[g][d] = sum_{n in [gmin,gmax)} agg3[d-slice][n]*dinv[n] ========
__global__ __launch_bounds__(64) void k_pool(const float* __restrict__ agg,  // [4][N1][16]
                                             const float* __restrict__ dinv,
                                             const int* __restrict__ gmin,
                                             const int* __restrict__ gmax,
                                             float* __restrict__ gpool,
                                             int* __restrict__ gcnt) {
    int g = blockIdx.x;
    int d = threadIdx.x;
    size_t off = (size_t)(d >> 4) * SLC16 + (d & 15);
    int lo = gmin[g], hi = gmax[g];
    float s = 0.f;
    for (int n = lo; n < hi; ++n) s += agg[off + (size_t)n * 16] * dinv[n];
    gpool[g * HIDDEN + d] = s;
    if (d == 0) gcnt[g] = (hi > lo) ? (hi - lo) : 0;
}

// ---------------- final: pooled @ W3 + cnt*b3, @ Wl + bl, softmax ----------------
__global__ __launch_bounds__(256) void k_final(const float* __restrict__ gpool,
                                               const int* __restrict__ gcnt,
                                               const float* __restrict__ W3,
                                               const float* __restrict__ b3,
                                               const float* __restrict__ Wl,
                                               const float* __restrict__ bl,
                                               float* __restrict__ out) {
    int wid = (blockIdx.x * blockDim.x + threadIdx.x) >> 6;
    int lane = threadIdx.x & 63;
    if (wid >= N_GRAPHS) return;
    float pre = gpool[wid * HIDDEN + lane];
    float cnt = (float)gcnt[wid];
    float emb = cnt * b3[lane];
    for (int k = 0; k < HIDDEN; ++k) {
        emb += __shfl(pre, k) * W3[k * HIDDEN + lane];
    }
    float p0 = emb * Wl[lane * 2 + 0];
    float p1 = emb * Wl[lane * 2 + 1];
    for (int d = 32; d > 0; d >>= 1) {
        p0 += __shfl_xor(p0, d);
        p1 += __shfl_xor(p1, d);
    }
    if (lane == 0) {
        float l0 = p0 + bl[0], l1 = p1 + bl[1];
        float m = fmaxf(l0, l1);
        float e0 = __expf(l0 - m), e1 = __expf(l1 - m);
        float inv = 1.f / (e0 + e1);
        out[wid * 2 + 0] = e0 * inv;
        out[wid * 2 + 1] = e1 * inv;
    }
}

extern "C" void kernel_launch(void* const* d_in, const int* in_sizes, int n_in,
                              void* d_out, int out_size, void* d_ws, size_t ws_size,
                              hipStream_t stream) {
    const float* x = (const float*)d_in[0];
    const int* edge = (const int*)d_in[1];
    const int* batch = (const int*)d_in[2];
    const float* W1 = (const float*)d_in[3];
    const float* b1 = (const float*)d_in[4];
    const float* W2 = (const float*)d_in[5];
    const float* b2 = (const float*)d_in[6];
    const float* W3 = (const float*)d_in[7];
    const float* b3 = (const float*)d_in[8];
    const float* Wl = (const float*)d_in[9];
    const float* bl = (const float*)d_in[10];
    float* out = (float*)d_out;

    const int* row = edge;
    const int* col = edge + N_EDGES;

    char* ws = (char*)d_ws;
    size_t off = 0;
    auto alloc = [&](size_t bytes) -> void* {
        void* p = ws + off;
        off = (off + bytes + 255) & ~(size_t)255;
        return p;
    };
    int* deg = (int*)alloc((size_t)N_NODES * 4);
    int* offs = (int*)alloc((size_t)N_NODES * 4);
    int* bsums = (int*)alloc(128 * 4);
    int* cursor = (int*)alloc((size_t)N_NODES * 4);
    float* dinv = (float*)alloc((size_t)N_NODES * 4);
    int* sorted = (int*)alloc((size_t)N_NODES * 4);
    int* hist = (int*)alloc(256 * 4);
    int* bincur = (int*)alloc(256 * 4);
    int* csr_src = (int*)alloc(((size_t)N_EDGES + 1024) * 4);
    u32* xsb = (u32*)alloc(SLC8 * 4);        // [N1][8] u32 = bf16 x*dinv (1 slice)
    u32* h1b = (u32*)alloc(4 * SLC8 * 4);    // [4][N1][8] u32 bf16 slices
    u32* h2b = (u32*)alloc(4 * SLC8 * 4);    // [4][N1][8]
    float* agg = (float*)alloc(4 * SLC16 * 4);  // [4][N1][16] f32 (shared by all layers)
    float* gpool = (float*)alloc((size_t)N_GRAPHS * HIDDEN * 4);
    int* gmin = (int*)alloc((size_t)N_GRAPHS * 4);
    int* gmax = (int*)alloc((size_t)N_GRAPHS * 4);
    int* gcnt = (int*)alloc((size_t)N_GRAPHS * 4);

    (void)hipMemsetAsync(deg, 0, (size_t)N_NODES * 4, stream);
    (void)hipMemsetAsync(cursor, 0, (size_t)N_NODES * 4, stream);
    (void)hipMemsetAsync(hist, 0, 256 * 4, stream);
    (void)hipMemsetAsync(gmin, 0x7f, (size_t)N_GRAPHS * 4, stream);
    (void)hipMemsetAsync(gmax, 0, (size_t)N_GRAPHS * 4, stream);

    const int EB = (N_EDGES + 255) / 256;
    const int NB1024 = (N_NODES + 1023) / 1024;
    const int NB256 = (N_NODES + 255) / 256;

    k_deg<<<EB, 256, 0, stream>>>(col, deg);
    k_scan_block<<<NB1024, 1024, 0, stream>>>(deg, offs, bsums);
    k_scan_top<<<1, 128, 0, stream>>>(bsums, NB1024);
    k_scan_add<<<NB1024, 1024, 0, stream>>>(offs, bsums);
    k_dinv<<<NB256, 256, 0, stream>>>(deg, dinv);

    // degree counting-sort (balances quad-wave degrees)
    k_hist<<<NB256, 256, 0, stream>>>(deg, hist);
    k_hscan<<<1, 256, 0, stream>>>(hist, bincur);
    k_place<<<NB256, 256, 0, stream>>>(deg, bincur, sorted);

    const int NCHUNKS = (N_EDGES + CHUNK_EDGES - 1) / CHUNK_EDGES;
    k_fill<<<NCHUNKS * NRANGES, 256, 0, stream>>>(row, col, offs, cursor, csr_src);
    k_prex<<<((int)(N1 * 8) + 255) / 256, 256, 0, stream>>>(x, dinv, xsb);
    k_zerosink<<<1, 64, 0, stream>>>(h1b, h2b);
    k_bounds<<<NB256, 256, 0, stream>>>(batch, gmin, gmax);

    // layer 1: 1 gather pass over xsb (3.2MB resident), dense W1 -> h1b slices
    k_gather<<<1 * NB_GATHER, 256, 0, stream>>>(xsb, offs, deg, csr_src, sorted, agg);
    k_dense1<<<2048, 256, 0, stream>>>(agg, dinv, W1, b1, h1b);
    // layer 2: 4 gather passes over h1b slices, dense W2 -> h2b
    k_gather<<<4 * NB_GATHER, 256, 0, stream>>>(h1b, offs, deg, csr_src, sorted, agg);
    k_dense2<<<2048, 256, 0, stream>>>(agg, dinv, W2, b2, h2b);
    // layer 3: 4 gather passes over h2b; pool (W3 commutes past pooling)
    k_gather<<<4 * NB_GATHER, 256, 0, stream>>>(h2b, offs, deg, csr_src, sorted, agg);
    k_pool<<<N_GRAPHS, 64, 0, stream>>>(agg, dinv, gmin, gmax, gpool, gcnt);
    k_final<<<(N_GRAPHS * 64 + 255) / 256, 256, 0, stream>>>(gpool, gcnt, W3, b3, Wl, bl, out);
}